// Round 14
// baseline (188.754 us; speedup 1.0000x reference)
//
#include <hip/hip_runtime.h>
#include <math.h>

// cSE channel self-attention, bf16-MFMA hi/lo, double-buffered 3-kernel path.
// x: [N=4][C=128][S=110592] f32.  out: same shape f32.
// energy = Q Q^T; attn_ij = exp(rowmin - e_ij)/sum (== reference softmax(max-e));
// out = attn @ Q.
//
// R14: R13 (134.1us best) with ONE change: gram uses 2-deep register
// prefetch (load cover ~2000 -> ~4500 cyc) to absorb DRAM tail latency at
// 1 block/CU where no co-resident block can hide a straggling load.
// finish + PV byte-identical to R13.

static constexpr int CN = 128;
static constexpr int SN = 110592;      // 48^3
static constexpr int NB = 4;

static constexpr int GB = 64;          // gram K-slices per batch (256 blocks = 1/CU)
static constexpr int GSL = SN / GB;    // 1728
static constexpr int GCH = GSL / 64;   // 27 chunks of K=64

static constexpr int PB = 432;         // pv s-blocks per batch (256 s each)
static constexpr int PCH = 4;          // chunks of 64 s per block

typedef float  f32x4  __attribute__((ext_vector_type(4)));
typedef short  bf16x8 __attribute__((ext_vector_type(8)));

// packed pair convert: dst[15:0]=bf16(a), dst[31:16]=bf16(b)  (RTNE)
__device__ __forceinline__ unsigned int cvtpk(float a, float b) {
    unsigned int r;
    asm("v_cvt_pk_bf16_f32 %0, %1, %2" : "=v"(r) : "v"(a), "v"(b));
    return r;
}
__device__ __forceinline__ unsigned short f2bh(float v) {
    unsigned int u = __float_as_uint(v);
    return (unsigned short)((u + 0x7fffu + ((u >> 16) & 1u)) >> 16);
}

// swizzled LDS fragment read: pitch 128B (gram) / 256B (pv), (row&7)<<4 XOR
__device__ __forceinline__ bf16x8 ldsfrag(const unsigned short* base, int row, int kbyte, int pitchB) {
    const char* p = reinterpret_cast<const char*>(base) + row * pitchB + (kbyte ^ ((row & 7) << 4));
    return *reinterpret_cast<const bf16x8*>(p);
}
__device__ __forceinline__ f32x4 mm(bf16x8 a, bf16x8 b, f32x4 c) {
    return __builtin_amdgcn_mfma_f32_16x16x32_bf16(a, b, c, 0, 0, 0);
}

// ---------------- K1: Gram via MFMA, hi/lo split, 64x64 tiles + K-split ----------------
// grid (GB, NB), block 512 (8 waves). Wave w: tile (wr,wc) = ((w>>1)&1, w&1),
// K-half kh = w>>2. Each block: K-slice of 1728, 27 chunks of K=64.
// LDS: 2 x ([128 c][64 k] bf16 hi + lo), pitch 128B, XOR-swizzled. 64 KB.
// 2-deep register prefetch. Epilogue: waves 4-7 dump acc into staging LDS,
// waves 0-3 add (fixed order), NT store.
template <bool ATOMIC>
__global__ __launch_bounds__(512, 1) void gram_mfma(const float* __restrict__ x,
                                                    float* __restrict__ dst) {
    __shared__ __align__(16) unsigned short lh[2][CN * 64];   // 16 KB each
    __shared__ __align__(16) unsigned short ll[2][CN * 64];
    const int bx = blockIdx.x, n = blockIdx.y;
    const int tid = threadIdx.x;
    const int lane = tid & 63;
    const int w = tid >> 6;                // 0..7
    const int wr = (w >> 1) & 1, wc = w & 1;   // 2x2 tile grid, tiles 64x64
    const int kh = w >> 2;                 // K-half 0/1
    const int ra = lane & 15, kg = lane >> 4;

    // staging mapping: thread -> (channel c, 16 consecutive k)
    const int c  = tid >> 2;               // 0..127
    const int ks = (tid & 3) << 4;         // 0,16,32,48
    const float* gq = x + (size_t)n * CN * SN + (size_t)c * SN + bx * GSL;

    f32x4 acc[4][4];
#pragma unroll
    for (int a = 0; a < 4; ++a)
#pragma unroll
        for (int b = 0; b < 4; ++b) acc[a][b] = (f32x4){0.f, 0.f, 0.f, 0.f};

    float4 st[2][4];                       // 2-deep register prefetch
    auto load_chunk = [&](int t, int slot) {
        const float4* p = reinterpret_cast<const float4*>(gq + t * 64 + ks);
        st[slot][0] = p[0]; st[slot][1] = p[1]; st[slot][2] = p[2]; st[slot][3] = p[3];
    };

    auto stage = [&](int buf, int slot) {
        unsigned int hw[8], lw[8];
#pragma unroll
        for (int r = 0; r < 4; ++r) {
            const unsigned int hp0 = cvtpk(st[slot][r].x, st[slot][r].y);
            const unsigned int hp1 = cvtpk(st[slot][r].z, st[slot][r].w);
            const unsigned int lp0 = cvtpk(st[slot][r].x - __uint_as_float(hp0 << 16),
                                           st[slot][r].y - __uint_as_float(hp0 & 0xffff0000u));
            const unsigned int lp1 = cvtpk(st[slot][r].z - __uint_as_float(hp1 << 16),
                                           st[slot][r].w - __uint_as_float(hp1 & 0xffff0000u));
            hw[r * 2] = hp0; hw[r * 2 + 1] = hp1;
            lw[r * 2] = lp0; lw[r * 2 + 1] = lp1;
        }
        char* ph = reinterpret_cast<char*>(lh[buf]) + c * 128;
        char* pl = reinterpret_cast<char*>(ll[buf]) + c * 128;
        const int sw = (c & 7) << 4;
        const int k2 = ks * 2;
        *reinterpret_cast<uint4*>(ph + (k2 ^ sw))        = make_uint4(hw[0], hw[1], hw[2], hw[3]);
        *reinterpret_cast<uint4*>(ph + ((k2 + 16) ^ sw)) = make_uint4(hw[4], hw[5], hw[6], hw[7]);
        *reinterpret_cast<uint4*>(pl + (k2 ^ sw))        = make_uint4(lw[0], lw[1], lw[2], lw[3]);
        *reinterpret_cast<uint4*>(pl + ((k2 + 16) ^ sw)) = make_uint4(lw[4], lw[5], lw[6], lw[7]);
    };

    auto compute = [&](int buf) {
        const unsigned short* LH = lh[buf];
        const unsigned short* LL = ll[buf];
        const int kb = (kh << 6) + (kg << 4);   // this wave's K-half
        bf16x8 ah[4], al[4], bh[4], bl[4];
#pragma unroll
        for (int it = 0; it < 4; ++it) {
            const int row = wr * 64 + it * 16 + ra;
            ah[it] = ldsfrag(LH, row, kb, 128);
            al[it] = ldsfrag(LL, row, kb, 128);
        }
#pragma unroll
        for (int jt = 0; jt < 4; ++jt) {
            const int row = wc * 64 + jt * 16 + ra;
            bh[jt] = ldsfrag(LH, row, kb, 128);
            bl[jt] = ldsfrag(LL, row, kb, 128);
        }
#pragma unroll
        for (int it = 0; it < 4; ++it)
#pragma unroll
            for (int jt = 0; jt < 4; ++jt) {
                acc[it][jt] = mm(ah[it], bh[jt], acc[it][jt]);
                acc[it][jt] = mm(ah[it], bl[jt], acc[it][jt]);
                acc[it][jt] = mm(al[it], bh[jt], acc[it][jt]);
            }
    };

    load_chunk(0, 0);
    load_chunk(1, 1);
    for (int t = 0; t < GCH; ++t) {
        const int slot = t & 1;
        stage(slot, slot);
        if (t + 2 < GCH) load_chunk(t + 2, slot);   // refill freed slot
        __syncthreads();                            // single barrier per chunk
        compute(slot);
    }

    // -------- epilogue: cross-K-half reduce via LDS (fixed order), then store --------
    __syncthreads();    // all compute LDS reads done before reuse
    float* ex = (w & 2) ? reinterpret_cast<float*>(ll[w & 1])
                        : reinterpret_cast<float*>(lh[w & 1]);
    if (w >= 4) {
#pragma unroll
        for (int it = 0; it < 4; ++it)
#pragma unroll
            for (int jt = 0; jt < 4; ++jt)
                *reinterpret_cast<f32x4*>(ex + (it * 4 + jt) * 256 + lane * 4) = acc[it][jt];
    }
    __syncthreads();
    if (w < 4) {
#pragma unroll
        for (int it = 0; it < 4; ++it)
#pragma unroll
            for (int jt = 0; jt < 4; ++jt)
                acc[it][jt] += *reinterpret_cast<const f32x4*>(ex + (it * 4 + jt) * 256 + lane * 4);

        const int q4 = kg << 2;
        if (!ATOMIC) {
            float* P = dst + (size_t)(n * GB + bx) * (CN * CN);
#pragma unroll
            for (int it = 0; it < 4; ++it)
#pragma unroll
                for (int jt = 0; jt < 4; ++jt)
#pragma unroll
                    for (int q = 0; q < 4; ++q)
                        __builtin_nontemporal_store(acc[it][jt][q],
                            &P[(wr * 64 + it * 16 + q4 + q) * CN + wc * 64 + jt * 16 + ra]);
        } else {
            float* E = dst + (size_t)n * CN * CN;
#pragma unroll
            for (int it = 0; it < 4; ++it)
#pragma unroll
                for (int jt = 0; jt < 4; ++jt)
#pragma unroll
                    for (int q = 0; q < 4; ++q)
                        atomicAdd(&E[(wr * 64 + it * 16 + q4 + q) * CN + wc * 64 + jt * 16 + ra], acc[it][jt][q]);
        }
    }
}

// ---------------- K2: fused reduce + softmin -> bf16-hi attention ----------------
// grid (CN, NB), block 256 (4 waves/row): wave w sums k in [w*16, w*16+16),
// LDS tree combine in fixed k-order (deterministic), wave 0 does softmax.
template <bool REDUCE>
__global__ __launch_bounds__(256) void finish_kernel(const float* __restrict__ src,
                                                     unsigned short* __restrict__ att_h) {
    __shared__ float red[8][64];
    const int i = blockIdx.x, n = blockIdx.y;
    const int tid = threadIdx.x;
    const int lane = tid & 63, w = tid >> 6;
    float e0 = 0.f, e1 = 0.f;
    if (REDUCE) {
        const float* p = src + (size_t)n * GB * (CN * CN) + i * CN;
#pragma unroll
        for (int k = 0; k < GB / 4; ++k) {
            const size_t o = (size_t)(w * (GB / 4) + k) * (CN * CN);
            e0 += __builtin_nontemporal_load(&p[o + lane]);
            e1 += __builtin_nontemporal_load(&p[o + lane + 64]);
        }
        red[w * 2][lane]     = e0;
        red[w * 2 + 1][lane] = e1;
        __syncthreads();
        if (w != 0) return;
        e0 = ((red[0][lane] + red[2][lane]) + (red[4][lane] + red[6][lane]));
        e1 = ((red[1][lane] + red[3][lane]) + (red[5][lane] + red[7][lane]));
    } else {
        if (w != 0) return;
        const float* E = src + ((size_t)n * CN + i) * CN;
        e0 = E[lane]; e1 = E[lane + 64];
    }
    float m = fminf(e0, e1);
#pragma unroll
    for (int off = 32; off > 0; off >>= 1) m = fminf(m, __shfl_xor(m, off));
    const float p0 = expf(m - e0);
    const float p1 = expf(m - e1);
    float s = p0 + p1;
#pragma unroll
    for (int off = 32; off > 0; off >>= 1) s += __shfl_xor(s, off);
    const float inv = 1.f / s;
    const size_t o = ((size_t)n * CN + i) * CN;
    att_h[o + lane]      = f2bh(p0 * inv);
    att_h[o + lane + 64] = f2bh(p1 * inv);
}

// ---------------- K3: out = attn @ Q via MFMA, double-buffered ----------------
// grid (PB, NB), block 512. Per block: 256 s (4 chunks of 64).
// A = attn-hi in registers. B = q-hi (cvt_pk staging). x loads normal,
// out stores NT. LDS: 2 x [64 s][128 j] bf16 hi, pitch 256B, XOR-swizzled.
__global__ __launch_bounds__(512, 4) void pv_mfma(const float* __restrict__ x,
                                                  const unsigned short* __restrict__ att_h,
                                                  float* __restrict__ out) {
    __shared__ __align__(16) unsigned short qh[2][64 * CN];
    const int bx = blockIdx.x, n = blockIdx.y;
    const int tid = threadIdx.x;
    const int lane = tid & 63;
    const int w = tid >> 6;                 // wave -> i-tile (rows w*16..w*16+15)
    const int ra = lane & 15, kg = lane >> 4;

    // A-fragments from global (attn L2/L3-resident across blocks)
    bf16x8 a_h[4];
    {
        const size_t rowoff = ((size_t)n * CN + w * 16 + ra) * CN + kg * 8;
        const unsigned short* Ah = att_h + rowoff;
#pragma unroll
        for (int kk = 0; kk < 4; ++kk)
            a_h[kk] = *reinterpret_cast<const bf16x8*>(Ah + kk * 32);
    }

    // staging mapping: thread -> 4x4 micro-block (j0..j0+3, s0..s0+3)
    const int j0 = (tid >> 4) * 4;          // 0..124
    const int s0 = (tid & 15) * 4;          // 0..60
    const float* gx = x + (size_t)n * CN * SN;
    const int sbase = bx * (PCH * 64);

    f32x4 st[4];
    auto load_chunk = [&](int sb) {
#pragma unroll
        for (int r = 0; r < 4; ++r)
            st[r] = *reinterpret_cast<const f32x4*>(gx + (size_t)(j0 + r) * SN + sb + s0);
    };

    auto stage = [&](int buf) {
        char* base = reinterpret_cast<char*>(qh[buf]);
#pragma unroll
        for (int r = 0; r < 4; ++r) {       // r = local s offset (compile-time)
            uint2 hv;
            hv.x = cvtpk(st[0][r], st[1][r]);
            hv.y = cvtpk(st[2][r], st[3][r]);
            const int s = s0 + r;
            const int off = s * 256 + ((j0 * 2) ^ ((s & 7) << 4));
            *reinterpret_cast<uint2*>(base + off) = hv;
        }
    };

    auto compute = [&](int buf, int sb) {
        const unsigned short* Q = qh[buf];
#pragma unroll
        for (int stile = 0; stile < 4; ++stile) {
            f32x4 acc = (f32x4){0.f, 0.f, 0.f, 0.f};
            const int srow = stile * 16 + ra;
#pragma unroll
            for (int kk = 0; kk < 4; ++kk) {
                const int kb = kk * 64 + (kg << 4);
                bf16x8 bh = ldsfrag(Q, srow, kb, 256);
                acc = mm(a_h[kk], bh, acc);
            }
            float* o = out + ((size_t)n * CN + w * 16 + (kg << 2)) * SN + sb + stile * 16 + ra;
#pragma unroll
            for (int q = 0; q < 4; ++q)
                __builtin_nontemporal_store(acc[q], o + (size_t)q * SN);
        }
    };

    load_chunk(sbase);
    for (int t = 0; t < PCH; ++t) {
        stage(t & 1);
        if (t < PCH - 1) load_chunk(sbase + (t + 1) * 64);
        __syncthreads();
        compute(t & 1, sbase + t * 64);
    }
}

extern "C" void kernel_launch(void* const* d_in, const int* in_sizes, int n_in,
                              void* d_out, int out_size, void* d_ws, size_t ws_size,
                              hipStream_t stream) {
    (void)in_sizes; (void)n_in; (void)out_size;
    const float* x = (const float*)d_in[0];
    float* out = (float*)d_out;

    // ws: [energy 256KB][att_h 128KB][partials 16.8MB]
    float* energy = (float*)d_ws;
    unsigned short* att_h = (unsigned short*)(energy + (size_t)NB * CN * CN);
    float* part = (float*)(att_h + (size_t)NB * CN * CN);
    const size_t need =
        (size_t)NB * CN * CN * sizeof(float) +
        (size_t)NB * CN * CN * sizeof(unsigned short) +
        (size_t)NB * GB * CN * CN * sizeof(float);

    if (ws_size >= need) {
        gram_mfma<false><<<dim3(GB, NB), 512, 0, stream>>>(x, part);
        finish_kernel<true><<<dim3(CN, NB), 256, 0, stream>>>(part, att_h);
    } else {
        hipMemsetAsync(energy, 0, (size_t)NB * CN * CN * sizeof(float), stream);
        gram_mfma<true><<<dim3(GB, NB), 512, 0, stream>>>(x, energy);
        finish_kernel<false><<<dim3(CN, NB), 256, 0, stream>>>(energy, att_h);
    }
    pv_mfma<<<dim3(PB, NB), 512, 0, stream>>>(x, att_h, out);
}

// Round 15
// 134.277 us; speedup vs baseline: 1.4057x; 1.4057x over previous
//
#include <hip/hip_runtime.h>
#include <math.h>

// cSE channel self-attention, bf16-MFMA hi/lo, double-buffered 3-kernel path.
// x: [N=4][C=128][S=110592] f32.  out: same shape f32.
// energy = Q Q^T; attn_ij = exp(rowmin - e_ij)/sum (== reference softmax(max-e));
// out = attn @ Q.
//
// R15: R14's 2-deep prefetch REDONE with static register indexing (rule #20:
// R14's st[slot] runtime index sent state to scratch -> VGPR 64, +218MB spill
// writes, gram 130us). Named st0/st1 + pair-unrolled chunk loop (13 pairs +
// tail). finish + PV byte-identical to R13 (134.1us best).

static constexpr int CN = 128;
static constexpr int SN = 110592;      // 48^3
static constexpr int NB = 4;

static constexpr int GB = 64;          // gram K-slices per batch (256 blocks = 1/CU)
static constexpr int GSL = SN / GB;    // 1728
static constexpr int GCH = GSL / 64;   // 27 chunks of K=64

static constexpr int PB = 432;         // pv s-blocks per batch (256 s each)
static constexpr int PCH = 4;          // chunks of 64 s per block

typedef float  f32x4  __attribute__((ext_vector_type(4)));
typedef short  bf16x8 __attribute__((ext_vector_type(8)));

// packed pair convert: dst[15:0]=bf16(a), dst[31:16]=bf16(b)  (RTNE)
__device__ __forceinline__ unsigned int cvtpk(float a, float b) {
    unsigned int r;
    asm("v_cvt_pk_bf16_f32 %0, %1, %2" : "=v"(r) : "v"(a), "v"(b));
    return r;
}
__device__ __forceinline__ unsigned short f2bh(float v) {
    unsigned int u = __float_as_uint(v);
    return (unsigned short)((u + 0x7fffu + ((u >> 16) & 1u)) >> 16);
}

// swizzled LDS fragment read: pitch 128B (gram) / 256B (pv), (row&7)<<4 XOR
__device__ __forceinline__ bf16x8 ldsfrag(const unsigned short* base, int row, int kbyte, int pitchB) {
    const char* p = reinterpret_cast<const char*>(base) + row * pitchB + (kbyte ^ ((row & 7) << 4));
    return *reinterpret_cast<const bf16x8*>(p);
}
__device__ __forceinline__ f32x4 mm(bf16x8 a, bf16x8 b, f32x4 c) {
    return __builtin_amdgcn_mfma_f32_16x16x32_bf16(a, b, c, 0, 0, 0);
}

// ---------------- K1: Gram via MFMA, hi/lo split, 64x64 tiles + K-split ----------------
// grid (GB, NB), block 512 (8 waves). Wave w: tile (wr,wc) = ((w>>1)&1, w&1),
// K-half kh = w>>2. Each block: K-slice of 1728, 27 chunks of K=64.
// LDS: 2 x ([128 c][64 k] bf16 hi + lo), pitch 128B, XOR-swizzled. 64 KB.
// 2-deep prefetch with NAMED buffers st0/st1 (static indices only).
template <bool ATOMIC>
__global__ __launch_bounds__(512, 1) void gram_mfma(const float* __restrict__ x,
                                                    float* __restrict__ dst) {
    __shared__ __align__(16) unsigned short lh[2][CN * 64];   // 16 KB each
    __shared__ __align__(16) unsigned short ll[2][CN * 64];
    const int bx = blockIdx.x, n = blockIdx.y;
    const int tid = threadIdx.x;
    const int lane = tid & 63;
    const int w = tid >> 6;                // 0..7
    const int wr = (w >> 1) & 1, wc = w & 1;   // 2x2 tile grid, tiles 64x64
    const int kh = w >> 2;                 // K-half 0/1
    const int ra = lane & 15, kg = lane >> 4;

    // staging mapping: thread -> (channel c, 16 consecutive k)
    const int c  = tid >> 2;               // 0..127
    const int ks = (tid & 3) << 4;         // 0,16,32,48
    const float* gq = x + (size_t)n * CN * SN + (size_t)c * SN + bx * GSL;

    f32x4 acc[4][4];
#pragma unroll
    for (int a = 0; a < 4; ++a)
#pragma unroll
        for (int b = 0; b < 4; ++b) acc[a][b] = (f32x4){0.f, 0.f, 0.f, 0.f};

    float4 st0[4], st1[4];                 // named prefetch buffers (static idx)
#define LOADC(dstbuf, t) { \
        const float4* p_ = reinterpret_cast<const float4*>(gq + (t) * 64 + ks); \
        dstbuf[0] = p_[0]; dstbuf[1] = p_[1]; dstbuf[2] = p_[2]; dstbuf[3] = p_[3]; }

#define STAGE(buf, sb) { \
        unsigned int hw[8], lw[8]; \
        _Pragma("unroll") \
        for (int r = 0; r < 4; ++r) { \
            const unsigned int hp0 = cvtpk(sb[r].x, sb[r].y); \
            const unsigned int hp1 = cvtpk(sb[r].z, sb[r].w); \
            const unsigned int lp0 = cvtpk(sb[r].x - __uint_as_float(hp0 << 16), \
                                           sb[r].y - __uint_as_float(hp0 & 0xffff0000u)); \
            const unsigned int lp1 = cvtpk(sb[r].z - __uint_as_float(hp1 << 16), \
                                           sb[r].w - __uint_as_float(hp1 & 0xffff0000u)); \
            hw[r * 2] = hp0; hw[r * 2 + 1] = hp1; \
            lw[r * 2] = lp0; lw[r * 2 + 1] = lp1; \
        } \
        char* ph = reinterpret_cast<char*>(lh[buf]) + c * 128; \
        char* pl = reinterpret_cast<char*>(ll[buf]) + c * 128; \
        const int sw = (c & 7) << 4; \
        const int k2 = ks * 2; \
        *reinterpret_cast<uint4*>(ph + (k2 ^ sw))        = make_uint4(hw[0], hw[1], hw[2], hw[3]); \
        *reinterpret_cast<uint4*>(ph + ((k2 + 16) ^ sw)) = make_uint4(hw[4], hw[5], hw[6], hw[7]); \
        *reinterpret_cast<uint4*>(pl + (k2 ^ sw))        = make_uint4(lw[0], lw[1], lw[2], lw[3]); \
        *reinterpret_cast<uint4*>(pl + ((k2 + 16) ^ sw)) = make_uint4(lw[4], lw[5], lw[6], lw[7]); }

    auto compute = [&](int buf) {
        const unsigned short* LH = lh[buf];
        const unsigned short* LL = ll[buf];
        const int kb = (kh << 6) + (kg << 4);   // this wave's K-half
        bf16x8 ah[4], al[4], bh[4], bl[4];
#pragma unroll
        for (int it = 0; it < 4; ++it) {
            const int row = wr * 64 + it * 16 + ra;
            ah[it] = ldsfrag(LH, row, kb, 128);
            al[it] = ldsfrag(LL, row, kb, 128);
        }
#pragma unroll
        for (int jt = 0; jt < 4; ++jt) {
            const int row = wc * 64 + jt * 16 + ra;
            bh[jt] = ldsfrag(LH, row, kb, 128);
            bl[jt] = ldsfrag(LL, row, kb, 128);
        }
#pragma unroll
        for (int it = 0; it < 4; ++it)
#pragma unroll
            for (int jt = 0; jt < 4; ++jt) {
                acc[it][jt] = mm(ah[it], bh[jt], acc[it][jt]);
                acc[it][jt] = mm(ah[it], bl[jt], acc[it][jt]);
                acc[it][jt] = mm(al[it], bh[jt], acc[it][jt]);
            }
    };

    LOADC(st0, 0)
    LOADC(st1, 1)
    // 13 pairs cover chunks 0..25; tail handles chunk 26. All indices static.
    for (int tb = 0; tb < GCH - 1; tb += 2) {
        // chunk tb: LDS buf 0, regs st0
        STAGE(0, st0)
        if (tb + 2 < GCH) LOADC(st0, tb + 2)
        __syncthreads();
        compute(0);
        // chunk tb+1: LDS buf 1, regs st1
        STAGE(1, st1)
        if (tb + 3 < GCH) LOADC(st1, tb + 3)
        __syncthreads();
        compute(1);
    }
    // tail: chunk 26 (GCH odd)
    STAGE(0, st0)
    __syncthreads();
    compute(0);
#undef LOADC
#undef STAGE

    // -------- epilogue: cross-K-half reduce via LDS (fixed order), then store --------
    __syncthreads();    // all compute LDS reads done before reuse
    float* ex = (w & 2) ? reinterpret_cast<float*>(ll[w & 1])
                        : reinterpret_cast<float*>(lh[w & 1]);
    if (w >= 4) {
#pragma unroll
        for (int it = 0; it < 4; ++it)
#pragma unroll
            for (int jt = 0; jt < 4; ++jt)
                *reinterpret_cast<f32x4*>(ex + (it * 4 + jt) * 256 + lane * 4) = acc[it][jt];
    }
    __syncthreads();
    if (w < 4) {
#pragma unroll
        for (int it = 0; it < 4; ++it)
#pragma unroll
            for (int jt = 0; jt < 4; ++jt)
                acc[it][jt] += *reinterpret_cast<const f32x4*>(ex + (it * 4 + jt) * 256 + lane * 4);

        const int q4 = kg << 2;
        if (!ATOMIC) {
            float* P = dst + (size_t)(n * GB + bx) * (CN * CN);
#pragma unroll
            for (int it = 0; it < 4; ++it)
#pragma unroll
                for (int jt = 0; jt < 4; ++jt)
#pragma unroll
                    for (int q = 0; q < 4; ++q)
                        __builtin_nontemporal_store(acc[it][jt][q],
                            &P[(wr * 64 + it * 16 + q4 + q) * CN + wc * 64 + jt * 16 + ra]);
        } else {
            float* E = dst + (size_t)n * CN * CN;
#pragma unroll
            for (int it = 0; it < 4; ++it)
#pragma unroll
                for (int jt = 0; jt < 4; ++jt)
#pragma unroll
                    for (int q = 0; q < 4; ++q)
                        atomicAdd(&E[(wr * 64 + it * 16 + q4 + q) * CN + wc * 64 + jt * 16 + ra], acc[it][jt][q]);
        }
    }
}

// ---------------- K2: fused reduce + softmin -> bf16-hi attention ----------------
// grid (CN, NB), block 256 (4 waves/row): wave w sums k in [w*16, w*16+16),
// LDS tree combine in fixed k-order (deterministic), wave 0 does softmax.
template <bool REDUCE>
__global__ __launch_bounds__(256) void finish_kernel(const float* __restrict__ src,
                                                     unsigned short* __restrict__ att_h) {
    __shared__ float red[8][64];
    const int i = blockIdx.x, n = blockIdx.y;
    const int tid = threadIdx.x;
    const int lane = tid & 63, w = tid >> 6;
    float e0 = 0.f, e1 = 0.f;
    if (REDUCE) {
        const float* p = src + (size_t)n * GB * (CN * CN) + i * CN;
#pragma unroll
        for (int k = 0; k < GB / 4; ++k) {
            const size_t o = (size_t)(w * (GB / 4) + k) * (CN * CN);
            e0 += __builtin_nontemporal_load(&p[o + lane]);
            e1 += __builtin_nontemporal_load(&p[o + lane + 64]);
        }
        red[w * 2][lane]     = e0;
        red[w * 2 + 1][lane] = e1;
        __syncthreads();
        if (w != 0) return;
        e0 = ((red[0][lane] + red[2][lane]) + (red[4][lane] + red[6][lane]));
        e1 = ((red[1][lane] + red[3][lane]) + (red[5][lane] + red[7][lane]));
    } else {
        if (w != 0) return;
        const float* E = src + ((size_t)n * CN + i) * CN;
        e0 = E[lane]; e1 = E[lane + 64];
    }
    float m = fminf(e0, e1);
#pragma unroll
    for (int off = 32; off > 0; off >>= 1) m = fminf(m, __shfl_xor(m, off));
    const float p0 = expf(m - e0);
    const float p1 = expf(m - e1);
    float s = p0 + p1;
#pragma unroll
    for (int off = 32; off > 0; off >>= 1) s += __shfl_xor(s, off);
    const float inv = 1.f / s;
    const size_t o = ((size_t)n * CN + i) * CN;
    att_h[o + lane]      = f2bh(p0 * inv);
    att_h[o + lane + 64] = f2bh(p1 * inv);
}

// ---------------- K3: out = attn @ Q via MFMA, double-buffered ----------------
// grid (PB, NB), block 512. Per block: 256 s (4 chunks of 64).
// A = attn-hi in registers. B = q-hi (cvt_pk staging). x loads normal,
// out stores NT. LDS: 2 x [64 s][128 j] bf16 hi, pitch 256B, XOR-swizzled.
__global__ __launch_bounds__(512, 4) void pv_mfma(const float* __restrict__ x,
                                                  const unsigned short* __restrict__ att_h,
                                                  float* __restrict__ out) {
    __shared__ __align__(16) unsigned short qh[2][64 * CN];
    const int bx = blockIdx.x, n = blockIdx.y;
    const int tid = threadIdx.x;
    const int lane = tid & 63;
    const int w = tid >> 6;                 // wave -> i-tile (rows w*16..w*16+15)
    const int ra = lane & 15, kg = lane >> 4;

    // A-fragments from global (attn L2/L3-resident across blocks)
    bf16x8 a_h[4];
    {
        const size_t rowoff = ((size_t)n * CN + w * 16 + ra) * CN + kg * 8;
        const unsigned short* Ah = att_h + rowoff;
#pragma unroll
        for (int kk = 0; kk < 4; ++kk)
            a_h[kk] = *reinterpret_cast<const bf16x8*>(Ah + kk * 32);
    }

    // staging mapping: thread -> 4x4 micro-block (j0..j0+3, s0..s0+3)
    const int j0 = (tid >> 4) * 4;          // 0..124
    const int s0 = (tid & 15) * 4;          // 0..60
    const float* gx = x + (size_t)n * CN * SN;
    const int sbase = bx * (PCH * 64);

    f32x4 st[4];
    auto load_chunk = [&](int sb) {
#pragma unroll
        for (int r = 0; r < 4; ++r)
            st[r] = *reinterpret_cast<const f32x4*>(gx + (size_t)(j0 + r) * SN + sb + s0);
    };

    auto stage = [&](int buf) {
        char* base = reinterpret_cast<char*>(qh[buf]);
#pragma unroll
        for (int r = 0; r < 4; ++r) {       // r = local s offset (compile-time)
            uint2 hv;
            hv.x = cvtpk(st[0][r], st[1][r]);
            hv.y = cvtpk(st[2][r], st[3][r]);
            const int s = s0 + r;
            const int off = s * 256 + ((j0 * 2) ^ ((s & 7) << 4));
            *reinterpret_cast<uint2*>(base + off) = hv;
        }
    };

    auto compute = [&](int buf, int sb) {
        const unsigned short* Q = qh[buf];
#pragma unroll
        for (int stile = 0; stile < 4; ++stile) {
            f32x4 acc = (f32x4){0.f, 0.f, 0.f, 0.f};
            const int srow = stile * 16 + ra;
#pragma unroll
            for (int kk = 0; kk < 4; ++kk) {
                const int kb = kk * 64 + (kg << 4);
                bf16x8 bh = ldsfrag(Q, srow, kb, 256);
                acc = mm(a_h[kk], bh, acc);
            }
            float* o = out + ((size_t)n * CN + w * 16 + (kg << 2)) * SN + sb + stile * 16 + ra;
#pragma unroll
            for (int q = 0; q < 4; ++q)
                __builtin_nontemporal_store(acc[q], o + (size_t)q * SN);
        }
    };

    load_chunk(sbase);
    for (int t = 0; t < PCH; ++t) {
        stage(t & 1);
        if (t < PCH - 1) load_chunk(sbase + (t + 1) * 64);
        __syncthreads();
        compute(t & 1, sbase + t * 64);
    }
}

extern "C" void kernel_launch(void* const* d_in, const int* in_sizes, int n_in,
                              void* d_out, int out_size, void* d_ws, size_t ws_size,
                              hipStream_t stream) {
    (void)in_sizes; (void)n_in; (void)out_size;
    const float* x = (const float*)d_in[0];
    float* out = (float*)d_out;

    // ws: [energy 256KB][att_h 128KB][partials 16.8MB]
    float* energy = (float*)d_ws;
    unsigned short* att_h = (unsigned short*)(energy + (size_t)NB * CN * CN);
    float* part = (float*)(att_h + (size_t)NB * CN * CN);
    const size_t need =
        (size_t)NB * CN * CN * sizeof(float) +
        (size_t)NB * CN * CN * sizeof(unsigned short) +
        (size_t)NB * GB * CN * CN * sizeof(float);

    if (ws_size >= need) {
        gram_mfma<false><<<dim3(GB, NB), 512, 0, stream>>>(x, part);
        finish_kernel<true><<<dim3(CN, NB), 256, 0, stream>>>(part, att_h);
    } else {
        hipMemsetAsync(energy, 0, (size_t)NB * CN * CN * sizeof(float), stream);
        gram_mfma<true><<<dim3(GB, NB), 512, 0, stream>>>(x, energy);
        finish_kernel<false><<<dim3(CN, NB), 256, 0, stream>>>(energy, att_h);
    }
    pv_mfma<<<dim3(PB, NB), 512, 0, stream>>>(x, att_h, out);
}